// Round 1
// baseline (220.869 us; speedup 1.0000x reference)
//
#include <hip/hip_runtime.h>

// MinVarianceWeightsLayer: for each of B SPD 64x64 fp32 matrices S,
// solve S z = 1, output w = z / sum(z) as [B, 64, 1] fp32.
//
// Strategy: one wave (64 lanes) per matrix, lane i owns row i entirely in
// VGPRs (64 floats). Gaussian elimination without pivoting (stable for SPD),
// fully unrolled so all row[] indices are compile-time constants; pivot-row
// broadcast via v_readlane (constant lane) -> no LDS traffic at all.

#define NN 64

__device__ __forceinline__ float rlane(float v, int lane) {
    // broadcast lane's value to all lanes; lane is a compile-time constant
    // after full unroll -> v_readlane_b32 (VALU, not the LDS pipe)
    return __int_as_float(__builtin_amdgcn_readlane(__float_as_int(v), lane));
}

__device__ __forceinline__ float frcp(float x) {
#if __has_builtin(__builtin_amdgcn_rcpf)
    return __builtin_amdgcn_rcpf(x);   // ~1 ulp; plenty vs 2e-3 abs threshold
#else
    return 1.0f / x;
#endif
}

__global__ __launch_bounds__(256) void minvar_kernel(const float* __restrict__ sigma,
                                                     float* __restrict__ out,
                                                     int batch) {
    const int lane = threadIdx.x & 63;
    const int wid  = threadIdx.x >> 6;     // 4 waves per block, 1 matrix each
    const int bid  = blockIdx.x * 4 + wid;
    if (bid >= batch) return;

    const float* __restrict__ p = sigma + (size_t)bid * (NN * NN) + (size_t)lane * NN;

    // Load own row (contiguous per lane; each 16 KB matrix is pulled through
    // L1 once per wave — compulsory HBM traffic only).
    float row[NN];
    #pragma unroll
    for (int j4 = 0; j4 < NN / 4; ++j4) {
        float4 v = reinterpret_cast<const float4*>(p)[j4];
        row[4 * j4 + 0] = v.x;
        row[4 * j4 + 1] = v.y;
        row[4 * j4 + 2] = v.z;
        row[4 * j4 + 3] = v.w;
    }

    float b = 1.0f;   // RHS: ones

    // ---- Forward elimination: row_i -= (S[i][k]/S[k][k]) * row_k, i > k ----
    // Lanes i <= k get factor 0 (wave-uniform no-op) so rows stay lockstep.
    #pragma unroll
    for (int k = 0; k < NN; ++k) {
        const float pivot = rlane(row[k], k);       // current S[k][k]
        const float invp  = frcp(pivot);
        const float nf    = (lane > k) ? (-row[k] * invp) : 0.0f;
        const float bk    = rlane(b, k);
        b = fmaf(nf, bk, b);
        #pragma unroll
        for (int j = k + 1; j < NN; ++j) {
            const float bc = rlane(row[j], k);      // pivot-row element (SGPR)
            row[j] = fmaf(nf, bc, row[j]);          // v_fmac with SGPR operand
        }
    }

    // ---- Back substitution: U z = y (U[i][j] = row[j] on lane i, j >= i) ----
    #pragma unroll
    for (int k = NN - 1; k >= 0; --k) {
        const float ukk = rlane(row[k], k);
        const float yk  = rlane(b, k);
        const float zk  = yk * frcp(ukk);
        const float upd = (lane < k) ? (-row[k]) : 0.0f;
        b = fmaf(upd, zk, b);       // eliminate column k from rows above
        if (lane == k) b = zk;      // lane k's solution is final
    }

    // ---- Normalize: w = z / sum(z) ----
    float total = b;
    #pragma unroll
    for (int off = 32; off >= 1; off >>= 1)
        total += __shfl_xor(total, off, 64);

    out[(size_t)bid * NN + lane] = b * frcp(total);
}

extern "C" void kernel_launch(void* const* d_in, const int* in_sizes, int n_in,
                              void* d_out, int out_size, void* d_ws, size_t ws_size,
                              hipStream_t stream) {
    const float* sigma = (const float*)d_in[0];
    float* out = (float*)d_out;
    const int batch = in_sizes[0] / (NN * NN);      // 8192
    const int blocks = (batch + 3) / 4;             // 4 matrices per 256-thr block
    minvar_kernel<<<blocks, 256, 0, stream>>>(sigma, out, batch);
}